// Round 1
// baseline (199.455 us; speedup 1.0000x reference)
//
#include <hip/hip_runtime.h>
#include <hip/hip_bf16.h>

typedef __attribute__((ext_vector_type(8))) short bf16x8;
typedef __attribute__((ext_vector_type(4))) float f32x4;
typedef __attribute__((ext_vector_type(8))) unsigned short ushort8v;
typedef __attribute__((ext_vector_type(4))) unsigned short ushort4v;

#define MFMA16(a, b, c) __builtin_amdgcn_mfma_f32_16x16x32_bf16((a), (b), (c), 0, 0, 0)

__device__ __forceinline__ unsigned short f2bf(float f) {
  union { float f; unsigned int u; } v; v.f = f;
  unsigned int r = v.u + 0x7FFFu + ((v.u >> 16) & 1u);
  return (unsigned short)(r >> 16);
}

// ---------------- transpose + cast: in (R,C) f32 -> out (C,R) bf16, batched ----------------
__global__ __launch_bounds__(256) void transpose_cast_kernel(
    const float* __restrict__ in, unsigned short* __restrict__ out, int R, int C) {
  __shared__ float tile[32][33];
  int c0 = blockIdx.x * 32, r0 = blockIdx.y * 32, b = blockIdx.z;
  const float* inb = in + (size_t)b * R * C;
  unsigned short* outb = out + (size_t)b * R * C;
  int tx = threadIdx.x & 31, ty = threadIdx.x >> 5;
#pragma unroll
  for (int k = 0; k < 4; ++k)
    tile[ty + 8 * k][tx] = inb[(size_t)(r0 + ty + 8 * k) * C + c0 + tx];
  __syncthreads();
#pragma unroll
  for (int k = 0; k < 4; ++k)
    outb[(size_t)(c0 + ty + 8 * k) * R + r0 + tx] = f2bf(tile[tx][ty + 8 * k]);
}

// ---------------- shared NT-GEMM core ----------------
// C[l][o] = sum_d A[l][d] * Bt[o][d], K = 512, block tile 128(l) x 64(o), BK = 64.
// 4 waves as 2x2; wave tile 64x32 = 4x2 fragments of 16x16.
// LDS rows padded to 80 elems (160 B stride -> 16B-aligned, <=4-way bank conflict).
__device__ __forceinline__ void gemm_acc(
    const unsigned short* __restrict__ A, const unsigned short* __restrict__ Bt,
    int l0, int o0, f32x4 acc[4][2],
    unsigned short (*As)[80], unsigned short (*Bs)[80]) {
  int tid = threadIdx.x, lane = tid & 63, wave = tid >> 6;
  int wl = wave >> 1, wo = wave & 1, lg = lane >> 4, lr = lane & 15;
  for (int kb = 0; kb < 512; kb += 64) {
    {
      int row = tid >> 1, cc = (tid & 1) * 32;
      const ushort8v* src = (const ushort8v*)(A + (size_t)(l0 + row) * 512 + kb + cc);
#pragma unroll
      for (int i = 0; i < 4; ++i) *(ushort8v*)&As[row][cc + 8 * i] = src[i];
      int row2 = tid >> 2, c2 = (tid & 3) * 16;
      const ushort8v* srcb = (const ushort8v*)(Bt + (size_t)(o0 + row2) * 512 + kb + c2);
      *(ushort8v*)&Bs[row2][c2] = srcb[0];
      *(ushort8v*)&Bs[row2][c2 + 8] = srcb[1];
    }
    __syncthreads();
#pragma unroll
    for (int kc = 0; kc < 2; ++kc) {
      bf16x8 af[4], bfr[2];
#pragma unroll
      for (int mf = 0; mf < 4; ++mf)
        af[mf] = *(const bf16x8*)&As[wl * 64 + mf * 16 + lr][kc * 32 + 8 * lg];
#pragma unroll
      for (int nf = 0; nf < 2; ++nf)
        bfr[nf] = *(const bf16x8*)&Bs[wo * 32 + nf * 16 + lr][kc * 32 + 8 * lg];
#pragma unroll
      for (int mf = 0; mf < 4; ++mf)
#pragma unroll
        for (int nf = 0; nf < 2; ++nf)
          acc[mf][nf] = MFMA16(af[mf], bfr[nf], acc[mf][nf]);
    }
    __syncthreads();
  }
}

// Q projection: C (8192, 512) bf16, plain store.
__global__ __launch_bounds__(256) void gemm_q_kernel(
    const unsigned short* __restrict__ A, const unsigned short* __restrict__ Bt,
    unsigned short* __restrict__ C) {
  __shared__ unsigned short As[128][80];
  __shared__ unsigned short Bs[64][80];
  f32x4 acc[4][2] = {};
  int l0 = blockIdx.x * 128, o0 = blockIdx.y * 64;
  gemm_acc(A, Bt, l0, o0, acc, As, Bs);
  int lane = threadIdx.x & 63, wave = threadIdx.x >> 6;
  int wl = wave >> 1, wo = wave & 1, lg = lane >> 4, lr = lane & 15;
#pragma unroll
  for (int mf = 0; mf < 4; ++mf)
#pragma unroll
    for (int nf = 0; nf < 2; ++nf)
#pragma unroll
      for (int r = 0; r < 4; ++r) {
        int row = l0 + wl * 64 + mf * 16 + 4 * lg + r;
        int col = o0 + wo * 32 + nf * 16 + lr;
        C[(size_t)row * 512 + col] = f2bf(acc[mf][nf][r]);
      }
}

// KV projection: cols [0,512) -> K (B*M, 512); cols [512,1024) -> Vt (B,H,64,M).
__global__ __launch_bounds__(256) void gemm_kv_kernel(
    const unsigned short* __restrict__ A, const unsigned short* __restrict__ Bt,
    unsigned short* __restrict__ K, unsigned short* __restrict__ Vt) {
  __shared__ unsigned short As[128][80];
  __shared__ unsigned short Bs[64][80];
  f32x4 acc[4][2] = {};
  int l0 = blockIdx.x * 128, o0 = blockIdx.y * 64;
  gemm_acc(A, Bt, l0, o0, acc, As, Bs);
  int lane = threadIdx.x & 63, wave = threadIdx.x >> 6;
  int wl = wave >> 1, wo = wave & 1, lg = lane >> 4, lr = lane & 15;
  if (o0 < 512) {
#pragma unroll
    for (int mf = 0; mf < 4; ++mf)
#pragma unroll
      for (int nf = 0; nf < 2; ++nf)
#pragma unroll
        for (int r = 0; r < 4; ++r) {
          int row = l0 + wl * 64 + mf * 16 + 4 * lg + r;
          int col = o0 + wo * 32 + nf * 16 + lr;
          K[(size_t)row * 512 + col] = f2bf(acc[mf][nf][r]);
        }
  } else {
    int b = l0 >> 11;
#pragma unroll
    for (int mf = 0; mf < 4; ++mf)
#pragma unroll
      for (int nf = 0; nf < 2; ++nf) {
        int m0 = (l0 & 2047) + wl * 64 + mf * 16 + 4 * lg;
        int oh = (o0 - 512) + wo * 32 + nf * 16 + lr;
        int h = oh >> 6, d = oh & 63;
        ushort4v pk;
#pragma unroll
        for (int r = 0; r < 4; ++r) pk[r] = f2bf(acc[mf][nf][r]);
        *(ushort4v*)&Vt[(size_t)((b * 8 + h) * 64 + d) * 2048 + m0] = pk;
      }
  }
}

// Out projection: out (B, 512, N) fp32 transposed store + bias.
__global__ __launch_bounds__(256) void gemm_out_kernel(
    const unsigned short* __restrict__ A, const unsigned short* __restrict__ Bt,
    float* __restrict__ Out, const float* __restrict__ bias) {
  __shared__ unsigned short As[128][80];
  __shared__ unsigned short Bs[64][80];
  f32x4 acc[4][2] = {};
  int l0 = blockIdx.x * 128, o0 = blockIdx.y * 64;
  gemm_acc(A, Bt, l0, o0, acc, As, Bs);
  int lane = threadIdx.x & 63, wave = threadIdx.x >> 6;
  int wl = wave >> 1, wo = wave & 1, lg = lane >> 4, lr = lane & 15;
#pragma unroll
  for (int mf = 0; mf < 4; ++mf)
#pragma unroll
    for (int nf = 0; nf < 2; ++nf) {
      int row = l0 + wl * 64 + mf * 16 + 4 * lg;  // l index, 4 consecutive
      int col = o0 + wo * 32 + nf * 16 + lr;      // dim index
      int b = row >> 11, n = row & 2047;
      float bv = bias[col];
      f32x4 v = acc[mf][nf];
#pragma unroll
      for (int r = 0; r < 4; ++r) v[r] += bv;
      *(f32x4*)&Out[((size_t)(b * 512 + col)) * 2048 + n] = v;
    }
}

// ---------------- flash attention ----------------
// grid (N/128, H, B); 4 waves x 32 q-rows; KV-tile 64; D = 64.
__global__ __launch_bounds__(256) void attn_kernel(
    const unsigned short* __restrict__ Qb, const unsigned short* __restrict__ Kb,
    const unsigned short* __restrict__ Vt, unsigned short* __restrict__ Ob) {
  __shared__ unsigned short Ks[64][80];
  __shared__ unsigned short Vs[64][80];
  __shared__ unsigned short Ps[4][32][80];
  int n0 = blockIdx.x * 128;
  int h = blockIdx.y, b = blockIdx.z;
  int tid = threadIdx.x, wave = tid >> 6, lane = tid & 63;
  int lg = lane >> 4, lr = lane & 15;
  int qrow0 = b * 2048 + n0 + wave * 32;
  const float scale = 0.125f;  // 64^-0.5

  bf16x8 qfr[2][2];
#pragma unroll
  for (int qf = 0; qf < 2; ++qf)
#pragma unroll
    for (int kc = 0; kc < 2; ++kc)
      qfr[qf][kc] = *(const bf16x8*)(Qb + (size_t)(qrow0 + qf * 16 + lr) * 512 +
                                     h * 64 + kc * 32 + 8 * lg);

  f32x4 acc[2][4] = {};
  float mrun[2][4], lrun[2][4];
#pragma unroll
  for (int qf = 0; qf < 2; ++qf)
#pragma unroll
    for (int r = 0; r < 4; ++r) { mrun[qf][r] = -1e30f; lrun[qf][r] = 0.0f; }

  for (int m0 = 0; m0 < 2048; m0 += 64) {
    {  // stage K tile (m x d) and Vt tile (d x m)
      int srow = tid >> 2, sc = (tid & 3) * 16;
      const ushort8v* ksrc =
          (const ushort8v*)(Kb + (size_t)(b * 2048 + m0 + srow) * 512 + h * 64 + sc);
      *(ushort8v*)&Ks[srow][sc] = ksrc[0];
      *(ushort8v*)&Ks[srow][sc + 8] = ksrc[1];
      const ushort8v* vsrc =
          (const ushort8v*)(Vt + (size_t)((b * 8 + h) * 64 + srow) * 2048 + m0 + sc);
      *(ushort8v*)&Vs[srow][sc] = vsrc[0];
      *(ushort8v*)&Vs[srow][sc + 8] = vsrc[1];
    }
    __syncthreads();

    // S = Q K^T  (raw, scale applied during softmax)
    f32x4 s[2][4] = {};
#pragma unroll
    for (int kc = 0; kc < 2; ++kc) {
      bf16x8 kf[4];
#pragma unroll
      for (int mf = 0; mf < 4; ++mf)
        kf[mf] = *(const bf16x8*)&Ks[mf * 16 + lr][kc * 32 + 8 * lg];
#pragma unroll
      for (int qf = 0; qf < 2; ++qf)
#pragma unroll
        for (int mf = 0; mf < 4; ++mf)
          s[qf][mf] = MFMA16(qfr[qf][kc], kf[mf], s[qf][mf]);
    }

    // online softmax (per q-row = per (qf, r), reduce over cols in 16-lane group)
#pragma unroll
    for (int qf = 0; qf < 2; ++qf)
#pragma unroll
      for (int r = 0; r < 4; ++r) {
        float mx = s[qf][0][r];
#pragma unroll
        for (int mf = 1; mf < 4; ++mf) mx = fmaxf(mx, s[qf][mf][r]);
        mx *= scale;  // scale > 0 so commutes with max
#pragma unroll
        for (int off = 1; off < 16; off <<= 1) mx = fmaxf(mx, __shfl_xor(mx, off, 64));
        float mnew = fmaxf(mrun[qf][r], mx);
        float corr = __expf(mrun[qf][r] - mnew);
        float rsum = 0.0f;
#pragma unroll
        for (int mf = 0; mf < 4; ++mf) {
          float p = __expf(fmaf(s[qf][mf][r], scale, -mnew));
          s[qf][mf][r] = p;
          rsum += p;
        }
#pragma unroll
        for (int off = 1; off < 16; off <<= 1) rsum += __shfl_xor(rsum, off, 64);
        lrun[qf][r] = lrun[qf][r] * corr + rsum;
        mrun[qf][r] = mnew;
#pragma unroll
        for (int df = 0; df < 4; ++df) acc[qf][df][r] *= corr;
      }

    // P -> LDS (re-fragment for PV A-operand)
#pragma unroll
    for (int qf = 0; qf < 2; ++qf)
#pragma unroll
      for (int mf = 0; mf < 4; ++mf)
#pragma unroll
        for (int r = 0; r < 4; ++r)
          Ps[wave][qf * 16 + 4 * lg + r][mf * 16 + lr] = f2bf(s[qf][mf][r]);

    // O += P V
#pragma unroll
    for (int kc = 0; kc < 2; ++kc) {
      bf16x8 pa[2], vf[4];
#pragma unroll
      for (int qf = 0; qf < 2; ++qf)
        pa[qf] = *(const bf16x8*)&Ps[wave][qf * 16 + lr][kc * 32 + 8 * lg];
#pragma unroll
      for (int df = 0; df < 4; ++df)
        vf[df] = *(const bf16x8*)&Vs[df * 16 + lr][kc * 32 + 8 * lg];
#pragma unroll
      for (int qf = 0; qf < 2; ++qf)
#pragma unroll
        for (int df = 0; df < 4; ++df)
          acc[qf][df] = MFMA16(pa[qf], vf[df], acc[qf][df]);
    }
    __syncthreads();
  }

  // epilogue: O = acc / l
#pragma unroll
  for (int qf = 0; qf < 2; ++qf)
#pragma unroll
    for (int df = 0; df < 4; ++df)
#pragma unroll
      for (int r = 0; r < 4; ++r) {
        float v = acc[qf][df][r] / lrun[qf][r];
        Ob[(size_t)(qrow0 + qf * 16 + 4 * lg + r) * 512 + h * 64 + df * 16 + lr] =
            f2bf(v);
      }
}

// ---------------- launcher ----------------
extern "C" void kernel_launch(void* const* d_in, const int* in_sizes, int n_in,
                              void* d_out, int out_size, void* d_ws, size_t ws_size,
                              hipStream_t stream) {
  const float* x   = (const float*)d_in[0];   // (4, 512, 2048)
  const float* ctx = (const float*)d_in[1];   // (4, 512, 2048)
  const float* Wq  = (const float*)d_in[2];   // (512, 512)
  const float* Wkv = (const float*)d_in[3];   // (512, 1024)
  const float* Wo  = (const float*)d_in[4];   // (512, 512)
  const float* bo  = (const float*)d_in[5];   // (512,)
  float* out = (float*)d_out;                 // (4, 512, 2048)

  char* ws = (char*)d_ws;
  unsigned short* xt   = (unsigned short*)(ws + 0);         // (8192, 512)
  unsigned short* ct   = (unsigned short*)(ws + 8388608);   // (8192, 512)
  unsigned short* Wqt  = (unsigned short*)(ws + 16777216);  // (512, 512)
  unsigned short* Wkvt = (unsigned short*)(ws + 17301504);  // (1024, 512)
  unsigned short* Wot  = (unsigned short*)(ws + 18350080);  // (512, 512)
  unsigned short* Qb   = (unsigned short*)(ws + 18874368);  // (8192, 512)
  unsigned short* Kb   = (unsigned short*)(ws + 27262976);  // (8192, 512)
  unsigned short* Vtb  = (unsigned short*)(ws + 35651584);  // (B,H,64,2048)
  unsigned short* Ob   = (unsigned short*)(ws + 44040192);  // (8192, 512)

  // transposes + casts
  transpose_cast_kernel<<<dim3(64, 16, 4), 256, 0, stream>>>(x, xt, 512, 2048);
  transpose_cast_kernel<<<dim3(64, 16, 4), 256, 0, stream>>>(ctx, ct, 512, 2048);
  transpose_cast_kernel<<<dim3(16, 16, 1), 256, 0, stream>>>(Wq, Wqt, 512, 512);
  transpose_cast_kernel<<<dim3(32, 16, 1), 256, 0, stream>>>(Wkv, Wkvt, 512, 1024);
  transpose_cast_kernel<<<dim3(16, 16, 1), 256, 0, stream>>>(Wo, Wot, 512, 512);

  // projections
  gemm_q_kernel<<<dim3(64, 8), 256, 0, stream>>>(xt, Wqt, Qb);
  gemm_kv_kernel<<<dim3(64, 16), 256, 0, stream>>>(ct, Wkvt, Kb, Vtb);

  // attention
  attn_kernel<<<dim3(16, 8, 4), 256, 0, stream>>>(Qb, Kb, Vtb, Ob);

  // output projection (+bias, transposed fp32 store)
  gemm_out_kernel<<<dim3(64, 8), 256, 0, stream>>>(Ob, Wot, out, bo);
}